// Round 15
// baseline (239.247 us; speedup 1.0000x reference)
//
#include <hip/hip_runtime.h>
#include <hip/hip_bf16.h>
#include <cstddef>
#include <cstdint>

#define B_   4
#define N_   8192
#define C_   768
#define H_   4
#define D_   192
#define CQ_  2304   // 3*C
#define M_   32768  // B*N

typedef __attribute__((ext_vector_type(8))) short short8_t;
typedef __attribute__((ext_vector_type(4))) float f32x4;

typedef const __attribute__((address_space(1))) uint gq_uint;
typedef __attribute__((address_space(3))) uint lds_uint;

__device__ inline ushort f2bf(float f){
  uint u = __float_as_uint(f);
  u += 0x7FFFu + ((u >> 16) & 1u);   // RNE; inputs are finite
  return (ushort)(u >> 16);
}
__device__ inline float bf2f(ushort u){ return __uint_as_float(((uint)u) << 16); }

// ---------------- fused fp32->bf16 for x and W + norm2 zeroing (1 dispatch) --
__global__ __launch_bounds__(256) void cvt_all(const float* __restrict__ x,
                                               ushort* __restrict__ xb,
                                               const float* __restrict__ Wq,
                                               ushort* __restrict__ Wb,
                                               float* __restrict__ norm2){
  int i = blockIdx.x * 256 + threadIdx.x;
  if (i < 6144) norm2[i] = 0.f;
  if (i < 6291456){
    float4 v = ((const float4*)x)[i];
    ushort4 o;
    o.x = f2bf(v.x); o.y = f2bf(v.y); o.z = f2bf(v.z); o.w = f2bf(v.w);
    ((ushort4*)xb)[i] = o;
  } else if (i < 6291456 + 442368){
    int j = i - 6291456;
    float4 v = ((const float4*)Wq)[j];
    ushort4 o;
    o.x = f2bf(v.x); o.y = f2bf(v.y); o.z = f2bf(v.z); o.w = f2bf(v.w);
    ((ushort4*)Wb)[j] = o;
  }
}

// ---------------- QKV projection: [32768,768] x [2304,768]^T -> bf16 [32768,2304]
// 128M x 256N tile, BK=32, 8 waves (2Mx4N, 64x64 each) -> acc=64 VGPR so
// 2 blocks/CU co-reside (LDS 48KiB, VGPR<=128 via launch_bounds(512,4)).
// R4-proven 2-barrier K-tile: {reads; lgkm0+bar; stage t+2 -> cur; 16 MFMA;
// vmcnt(3)+bar}. LDS invariant: LDS[r][slot] = global[r][(slot^(r&3))*16B].
// Fused: column sum-of-squares for q,k (bx < 6).
__global__ __launch_bounds__(512, 4) void gemm_qkvv(const ushort* __restrict__ A,
                                                    const ushort* __restrict__ W,
                                                    ushort* __restrict__ Cq,
                                                    float* __restrict__ norm2){
  extern __shared__ ushort lds[];   // 2 buf x (A 128x32 + B 256x32) = 49152 B
  const int t = threadIdx.x;
  // XCD-aware swizzle: 2304 = 8 * 288
  const int bid = blockIdx.x;
  const int wg  = (bid & 7) * 288 + (bid >> 3);
  const int by = wg / 9, bx = wg % 9;
  const int m0 = by * 128, n0 = bx * 256;
  const int wid = t >> 6, lane = t & 63;
  const int wr = wid >> 2, wc = wid & 3;        // wave tile 64(M) x 64(N)
  const int lr = lane & 15, lg = lane >> 4;
  // staging lane geometry: 16 rows/wave/inst, 4 slots of 16B, pre-swizzled
  const int srow4  = lane >> 2;
  const int sslot4 = (lane & 3) ^ (srow4 & 3);
  const int slx = (lg ^ (lr & 3)) * 8;          // frag-read swizzled slot (ushorts)

  f32x4 acc[4][4];
  #pragma unroll
  for (int i = 0; i < 4; ++i)
    #pragma unroll
    for (int j = 0; j < 4; ++j)
      acc[i][j] = (f32x4){0.f, 0.f, 0.f, 0.f};

  #define STAGE_A(KT, LBASE)                                                    \
    __builtin_amdgcn_global_load_lds(                                           \
        (gq_uint*)(const void*)(A + (size_t)(m0 + wid*16 + srow4) * 768         \
                                + (KT) * 32 + sslot4 * 8),                      \
        (lds_uint*)(void*)((LBASE) + wid * 512), 16, 0, 0);

  #define STAGE_W(KT, LBASE)                                                    \
    _Pragma("unroll")                                                           \
    for (int r_ = 0; r_ < 2; ++r_){                                             \
      __builtin_amdgcn_global_load_lds(                                         \
          (gq_uint*)(const void*)(W + (size_t)(n0 + r_*128 + wid*16 + srow4) * 768 \
                                  + (KT) * 32 + sslot4 * 8),                    \
          (lds_uint*)(void*)((LBASE) + r_*4096 + wid * 512), 16, 0, 0);         \
    }

  #define RD_A(DST)                                                             \
    _Pragma("unroll") for (int fm = 0; fm < 4; ++fm)                            \
      DST[fm] = *(const short8_t*)(bA + (wr*64 + fm*16 + lr) * 32 + slx);

  #define RD_B(DST)                                                             \
    _Pragma("unroll") for (int fn = 0; fn < 4; ++fn)                            \
      DST[fn] = *(const short8_t*)(bB + (wc*64 + fn*16 + lr) * 32 + slx);

  #define MM(AR, BR)                                                            \
    __builtin_amdgcn_s_setprio(1);                                              \
    _Pragma("unroll") for (int fm = 0; fm < 4; ++fm)                            \
    _Pragma("unroll") for (int fn = 0; fn < 4; ++fn)                            \
      acc[fm][fn] = __builtin_amdgcn_mfma_f32_16x16x32_bf16(                    \
          AR[fm], BR[fn], acc[fm][fn], 0, 0, 0);                                \
    __builtin_amdgcn_s_setprio(0);

  // prologue: tiles 0,1 into buf0,buf1 (3 loads each)
  STAGE_A(0, lds);          STAGE_W(0, lds + 4096);
  STAGE_A(1, lds + 12288);  STAGE_W(1, lds + 12288 + 4096);
  asm volatile("s_waitcnt vmcnt(3)" ::: "memory");   // t0 landed; t1 in flight
  __builtin_amdgcn_s_barrier();
  __builtin_amdgcn_sched_barrier(0);

  short8_t af[4], bf[4];

  #pragma unroll 2
  for (int kt = 0; kt < 22; ++kt){
    const ushort* bA = lds + (kt & 1) * 12288;
    const ushort* bB = bA + 4096;
    ushort* nA = lds + (kt & 1) * 12288;       // t+2 has same parity
    RD_A(af); RD_B(bf);
    asm volatile("s_waitcnt lgkmcnt(0)" ::: "memory");  // reads drained...
    __builtin_amdgcn_sched_barrier(0);
    __builtin_amdgcn_s_barrier();                       // ...before anyone overwrites
    __builtin_amdgcn_sched_barrier(0);
    STAGE_A(kt + 2, nA);
    STAGE_W(kt + 2, nA + 4096);
    MM(af, bf);
    asm volatile("s_waitcnt vmcnt(3)" ::: "memory");    // t+1 retired, t+2 in flight
    __builtin_amdgcn_s_barrier();
    __builtin_amdgcn_sched_barrier(0);
  }
  // tile 22 (no staging)
  {
    const ushort* bA = lds;          // 22 & 1 == 0
    const ushort* bB = bA + 4096;
    RD_A(af); RD_B(bf);
    asm volatile("s_waitcnt lgkmcnt(0)" ::: "memory");
    __builtin_amdgcn_sched_barrier(0);
    MM(af, bf);
    asm volatile("s_waitcnt vmcnt(0)" ::: "memory");    // t23 retired
    __builtin_amdgcn_s_barrier();                       // published
    __builtin_amdgcn_sched_barrier(0);
  }
  // tile 23
  {
    const ushort* bA = lds + 12288;
    const ushort* bB = bA + 4096;
    RD_A(af); RD_B(bf);
    asm volatile("s_waitcnt lgkmcnt(0)" ::: "memory");
    __builtin_amdgcn_sched_barrier(0);
    MM(af, bf);
  }
  #undef STAGE_A
  #undef STAGE_W
  #undef RD_A
  #undef RD_B
  #undef MM

  // epilogue: C write (bf16)
  #pragma unroll
  for (int fm = 0; fm < 4; ++fm)
    #pragma unroll
    for (int fn = 0; fn < 4; ++fn)
      #pragma unroll
      for (int r = 0; r < 4; ++r){
        int m = m0 + wr*64 + fm*16 + lg*4 + r;
        int c = n0 + wc*64 + fn*16 + lr;
        Cq[(size_t)m * CQ_ + c] = f2bf(acc[fm][fn][r]);
      }

  // fused column sum-of-squares for q,k columns (n0 < 1536)
  if (bx < 6){
    const int b = m0 >> 13;
    #pragma unroll
    for (int fn = 0; fn < 4; ++fn){
      float s = 0.f;
      #pragma unroll
      for (int fm = 0; fm < 4; ++fm)
        #pragma unroll
        for (int r = 0; r < 4; ++r)
          s = fmaf(acc[fm][fn][r], acc[fm][fn][r], s);
      s += __shfl_xor(s, 16);
      s += __shfl_xor(s, 32);
      if (lg == 0)
        atomicAdd(&norm2[b * 1536 + n0 + wc*64 + fn*16 + lr], s);
    }
  }
}

// ---------------- Gram via MFMA: S_part[kc][bh][d][e] partial sums ----------
// 512 threads (8 waves, 2d x 4e). Pair-packed transposed LDS: dword (np,d) =
// {bf16(n=2np,d), bf16(n=2np+1,d)} -> fragments are plain ds_read_b32.
// Reg-staged double-buffered global loads; all cross-wave sync via __syncthreads.
__global__ __launch_bounds__(512) void gram_mfma(const ushort* __restrict__ Qk,
                                                 float* __restrict__ Sp){
  const int kc = blockIdx.x;      // 16 K-chunks of 512 rows
  const int bh = blockIdx.y;      // 16
  const int b = bh >> 2, h = bh & 3;
  __shared__ __align__(16) uint pk[2][2][3232];   // [buf][mat][np*202 + d], d<192
  const int t = threadIdx.x;
  const int wid = t >> 6, lane = t & 63;
  const int wd = wid >> 2, we = wid & 3;          // wave tile: 96(d) x 48(e)
  const int lr = lane & 15, lg = lane >> 4;

  f32x4 acc[6][3];
  #pragma unroll
  for (int i = 0; i < 6; ++i)
    #pragma unroll
    for (int j = 0; j < 3; ++j)
      acc[i][j] = (f32x4){0.f, 0.f, 0.f, 0.f};

  const uint* gq = (const uint*)Qk + (size_t)b * N_ * 1152;   // dword rows

  uint r0[6], r1[6];
  #define GLOAD(IT)                                                             \
    _Pragma("unroll") for (int u = 0; u < 6; ++u){                              \
      int id = u*512 + t, mat = id/1536, rem = id - mat*1536;                   \
      int np = rem/96, c = rem - np*96;                                         \
      const uint* p = gq + (size_t)(kc*512 + (IT)*32 + 2*np)*1152               \
                         + (mat ? 384 + h*96 : h*96) + c;                       \
      r0[u] = p[0]; r1[u] = p[1152];                                            \
    }
  #define LWRITE(BUF)                                                           \
    _Pragma("unroll") for (int u = 0; u < 6; ++u){                              \
      int id = u*512 + t, mat = id/1536, rem = id - mat*1536;                   \
      int np = rem/96, c = rem - np*96;                                         \
      uint o0 = (r0[u] & 0xFFFFu) | (r1[u] << 16);                              \
      uint o1 = (r0[u] >> 16) | (r1[u] & 0xFFFF0000u);                          \
      *(uint2*)&pk[BUF][mat][np*202 + 2*c] = (uint2){o0, o1};                   \
    }

  GLOAD(0);
  LWRITE(0);
  __syncthreads();

  for (int it = 0; it < 16; ++it){
    const int cur = it & 1;
    if (it < 15) GLOAD(it + 1);     // in flight under compute
    union { uint u[4]; short8_t v; } af[6], bf[3];
    #pragma unroll
    for (int i = 0; i < 6; ++i){
      int d = wd * 96 + i * 16 + lr;
      #pragma unroll
      for (int p = 0; p < 4; ++p)
        af[i].u[p] = pk[cur][0][(lg*4 + p)*202 + d];
    }
    #pragma unroll
    for (int j = 0; j < 3; ++j){
      int e = we * 48 + j * 16 + lr;
      #pragma unroll
      for (int p = 0; p < 4; ++p)
        bf[j].u[p] = pk[cur][1][(lg*4 + p)*202 + e];
    }
    #pragma unroll
    for (int i = 0; i < 6; ++i)
      #pragma unroll
      for (int j = 0; j < 3; ++j)
        acc[i][j] = __builtin_amdgcn_mfma_f32_16x16x32_bf16(af[i].v, bf[j].v, acc[i][j], 0, 0, 0);
    if (it < 15) LWRITE(cur ^ 1);   // opposite buffer: no WAR with current reads
    __syncthreads();
  }
  #undef GLOAD
  #undef LWRITE

  float* base = Sp + (size_t)(kc * 16 + bh) * 192 * 192;
  #pragma unroll
  for (int i = 0; i < 6; ++i)
    #pragma unroll
    for (int j = 0; j < 3; ++j)
      #pragma unroll
      for (int r = 0; r < 4; ++r){
        int d = wd * 96 + i * 16 + lg * 4 + r;
        int e = we * 48 + j * 16 + lr;
        base[(size_t)d * 192 + e] = acc[i][j][r];
      }
}

// ---------------- softmax rows: reduce 16 partial slices + temp + l2 fold ---
__global__ __launch_bounds__(256) void softmax_k(const float* __restrict__ Sp,
                                                 const float* __restrict__ norm2,
                                                 const float* __restrict__ temp,
                                                 ushort* __restrict__ attn){
  const int wid  = blockIdx.x * 4 + (threadIdx.x >> 6);  // row id [0,3072)
  const int lane = threadIdx.x & 63;
  const int bh = wid / 192, d = wid % 192;
  const int b = bh >> 2, h = bh & 3;
  const float nq = sqrtf(norm2[b*1536 + h*192 + d]);
  const float sc = temp[h] / fmaxf(nq, 1e-12f);
  const float* Sr = Sp + ((size_t)bh * 192 + d) * 192;
  float l[3];
  #pragma unroll
  for (int u = 0; u < 3; ++u){
    int e = lane + u * 64;
    float s = 0.f;
    #pragma unroll
    for (int kc = 0; kc < 16; ++kc)
      s += Sr[(size_t)kc * (16*192*192) + e];
    float nk = sqrtf(norm2[b*1536 + 768 + h*192 + e]);
    l[u] = s * sc / fmaxf(nk, 1e-12f);
  }
  float m = fmaxf(l[0], fmaxf(l[1], l[2]));
  #pragma unroll
  for (int off = 32; off; off >>= 1) m = fmaxf(m, __shfl_xor(m, off));
  float p[3], s = 0.f;
  #pragma unroll
  for (int u = 0; u < 3; ++u){ p[u] = expf(l[u] - m); s += p[u]; }
  #pragma unroll
  for (int off = 32; off; off >>= 1) s += __shfl_xor(s, off);
  float inv = 1.f / s;
  ushort* ar = attn + ((size_t)bh * 192 + d) * 192;
  #pragma unroll
  for (int u = 0; u < 3; ++u) ar[lane + u*64] = f2bf(p[u] * inv);
}

// ---------------- out[n][h*192+d] = sum_e V[n][e] * attn[d][e] --------------
__global__ __launch_bounds__(256) void out_gemm(const ushort* __restrict__ Q,
                                                const ushort* __restrict__ attn,
                                                float* __restrict__ out){
  const int bh = blockIdx.y;
  const int b = bh >> 2, h = bh & 3;
  const int n0 = blockIdx.x * 128;
  const int t = threadIdx.x, w = t >> 6, lane = t & 63;
  const int wn = w & 1, wd = w >> 1;
  const int lr = lane & 15, lg = lane >> 4;
  f32x4 acc[4][6];
  #pragma unroll
  for (int i = 0; i < 4; ++i)
    #pragma unroll
    for (int j = 0; j < 6; ++j)
      acc[i][j] = (f32x4){0.f, 0.f, 0.f, 0.f};

  const ushort* Vbase = Q + 1536 + h * 192;
  const ushort* Abase = attn + (size_t)bh * 192 * 192;

  #pragma unroll
  for (int kk = 0; kk < 6; ++kk){
    const int e = kk * 32 + lg * 8;
    short8_t av[4], bv[6];
    #pragma unroll
    for (int f = 0; f < 4; ++f){
      int n = n0 + wn*64 + f*16 + lr;
      av[f] = *(const short8_t*)(Vbase + (size_t)(b*N_ + n) * CQ_ + e);
    }
    #pragma unroll
    for (int f = 0; f < 6; ++f){
      int d = wd*96 + f*16 + lr;
      bv[f] = *(const short8_t*)(Abase + d * 192 + e);
    }
    #pragma unroll
    for (int i = 0; i < 4; ++i)
      #pragma unroll
      for (int j = 0; j < 6; ++j)
        acc[i][j] = __builtin_amdgcn_mfma_f32_16x16x32_bf16(av[i], bv[j], acc[i][j], 0, 0, 0);
  }
  #pragma unroll
  for (int i = 0; i < 4; ++i)
    #pragma unroll
    for (int j = 0; j < 6; ++j)
      #pragma unroll
      for (int r = 0; r < 4; ++r){
        int n = n0 + wn*64 + i*16 + lg*4 + r;
        int c = h*192 + wd*96 + j*16 + lr;
        out[(size_t)(b*N_ + n) * 768 + c] = acc[i][j][r];
      }
}

// ---------------------------------------------------------------------------
extern "C" void kernel_launch(void* const* d_in, const int* in_sizes, int n_in,
                              void* d_out, int out_size, void* d_ws, size_t ws_size,
                              hipStream_t stream){
  const float* x    = (const float*)d_in[0];
  const float* Wq   = (const float*)d_in[1];
  const float* temp = (const float*)d_in[2];
  float* out = (float*)d_out;
  char* ws = (char*)d_ws;

  // workspace layout (bytes) — S_part/attn overlay xb (dead after gemm_qkvv)
  ushort* xb    = (ushort*)(ws + 0);          //  50,331,648 (dead after gemm)
  float*  S_part= (float*)(ws + 0);           //  37,748,736 (16 slices)
  ushort* attn  = (ushort*)(ws + 37748736);   //   1,179,648
  ushort* Wb    = (ushort*)(ws + 50331648);   //   3,538,944
  ushort* qkvv  = (ushort*)(ws + 53870592);   // 150,994,944
  float*  norm2 = (float*)(ws + 204865536);   //      24,576

  static_assert(sizeof(ushort) == 2, "");
  hipFuncSetAttribute((const void*)gemm_qkvv,
                      hipFuncAttributeMaxDynamicSharedMemorySize, 49152);

  cvt_all<<<26304, 256, 0, stream>>>(x, xb, Wq, Wb, norm2);

  gemm_qkvv<<<2304, 512, 49152, stream>>>(xb, Wb, qkvv, norm2);

  gram_mfma<<<dim3(16, 16), 512, 0, stream>>>(qkvv, S_part);
  softmax_k<<<768, 256, 0, stream>>>(S_part, norm2, temp, attn);
  out_gemm<<<dim3(64, 16), 256, 0, stream>>>(qkvv, attn, out);
}

// Round 16
// 238.474 us; speedup vs baseline: 1.0032x; 1.0032x over previous
//
#include <hip/hip_runtime.h>
#include <hip/hip_bf16.h>
#include <cstddef>
#include <cstdint>

#define B_   4
#define N_   8192
#define C_   768
#define H_   4
#define D_   192
#define CQ_  2304   // 3*C
#define M_   32768  // B*N

typedef __attribute__((ext_vector_type(8))) short short8_t;
typedef __attribute__((ext_vector_type(4))) float f32x4;

typedef const __attribute__((address_space(1))) uint gq_uint;
typedef __attribute__((address_space(3))) uint lds_uint;

__device__ inline ushort f2bf(float f){
  uint u = __float_as_uint(f);
  u += 0x7FFFu + ((u >> 16) & 1u);   // RNE; inputs are finite
  return (ushort)(u >> 16);
}
__device__ inline float bf2f(ushort u){ return __uint_as_float(((uint)u) << 16); }

// ---------------- fused fp32->bf16 for x and W + norm2 zeroing (1 dispatch) --
__global__ __launch_bounds__(256) void cvt_all(const float* __restrict__ x,
                                               ushort* __restrict__ xb,
                                               const float* __restrict__ Wq,
                                               ushort* __restrict__ Wb,
                                               float* __restrict__ norm2){
  int i = blockIdx.x * 256 + threadIdx.x;
  if (i < 6144) norm2[i] = 0.f;
  if (i < 6291456){
    float4 v = ((const float4*)x)[i];
    ushort4 o;
    o.x = f2bf(v.x); o.y = f2bf(v.y); o.z = f2bf(v.z); o.w = f2bf(v.w);
    ((ushort4*)xb)[i] = o;
  } else if (i < 6291456 + 442368){
    int j = i - 6291456;
    float4 v = ((const float4*)Wq)[j];
    ushort4 o;
    o.x = f2bf(v.x); o.y = f2bf(v.y); o.z = f2bf(v.z); o.w = f2bf(v.w);
    ((ushort4*)Wb)[j] = o;
  }
}

// ---------------- QKV projection: [32768,768] x [2304,768]^T -> bf16 [32768,2304]
// 128M x 256N tile, BK=32, 8 waves (2Mx4N, 64x64 each), 2 blocks/CU.
// LDS invariant: LDS[row][s] = global[row][(s ^ key(row))*16B], key(row)=(row>>2)&3.
// [R15 bug: key=(row&3) aliases bank row-parity -> 4-way conflict within
//  quarter-wave; key=(row>>2)&3 gives 8 regions x 2 lanes = conflict-free.]
// R4-proven 2-barrier K-tile: {reads; lgkm0+bar; stage t+2 -> cur; 16 MFMA;
// vmcnt(3)+bar}. Fused: column sum-of-squares for q,k (bx < 6).
__global__ __launch_bounds__(512, 4) void gemm_qkvv(const ushort* __restrict__ A,
                                                    const ushort* __restrict__ W,
                                                    ushort* __restrict__ Cq,
                                                    float* __restrict__ norm2){
  extern __shared__ ushort lds[];   // 2 buf x (A 128x32 + B 256x32) = 49152 B
  const int t = threadIdx.x;
  // XCD-aware swizzle: 2304 = 8 * 288
  const int bid = blockIdx.x;
  const int wg  = (bid & 7) * 288 + (bid >> 3);
  const int by = wg / 9, bx = wg % 9;
  const int m0 = by * 128, n0 = bx * 256;
  const int wid = t >> 6, lane = t & 63;
  const int wr = wid >> 2, wc = wid & 3;        // wave tile 64(M) x 64(N)
  const int lr = lane & 15, lg = lane >> 4;
  // staging lane geometry: 16 rows/wave/inst, 4 slots of 16B.
  // staged row = chunk*16 + (lane>>2); key(row) = (row>>2)&3 = (lane>>4)&3.
  const int srow4  = lane >> 2;
  const int sslot4 = (lane & 3) ^ ((lane >> 4) & 3);
  // frag-read slot: row = base16 + lr -> key = (lr>>2)&3
  const int slx = (lg ^ ((lr >> 2) & 3)) * 8;   // ushort offset

  f32x4 acc[4][4];
  #pragma unroll
  for (int i = 0; i < 4; ++i)
    #pragma unroll
    for (int j = 0; j < 4; ++j)
      acc[i][j] = (f32x4){0.f, 0.f, 0.f, 0.f};

  #define STAGE_A(KT, LBASE)                                                    \
    __builtin_amdgcn_global_load_lds(                                           \
        (gq_uint*)(const void*)(A + (size_t)(m0 + wid*16 + srow4) * 768         \
                                + (KT) * 32 + sslot4 * 8),                      \
        (lds_uint*)(void*)((LBASE) + wid * 512), 16, 0, 0);

  #define STAGE_W(KT, LBASE)                                                    \
    _Pragma("unroll")                                                           \
    for (int r_ = 0; r_ < 2; ++r_){                                             \
      __builtin_amdgcn_global_load_lds(                                         \
          (gq_uint*)(const void*)(W + (size_t)(n0 + r_*128 + wid*16 + srow4) * 768 \
                                  + (KT) * 32 + sslot4 * 8),                    \
          (lds_uint*)(void*)((LBASE) + r_*4096 + wid * 512), 16, 0, 0);         \
    }

  #define RD_A(DST)                                                             \
    _Pragma("unroll") for (int fm = 0; fm < 4; ++fm)                            \
      DST[fm] = *(const short8_t*)(bA + (wr*64 + fm*16 + lr) * 32 + slx);

  #define RD_B(DST)                                                             \
    _Pragma("unroll") for (int fn = 0; fn < 4; ++fn)                            \
      DST[fn] = *(const short8_t*)(bB + (wc*64 + fn*16 + lr) * 32 + slx);

  #define MM(AR, BR)                                                            \
    __builtin_amdgcn_s_setprio(1);                                              \
    _Pragma("unroll") for (int fm = 0; fm < 4; ++fm)                            \
    _Pragma("unroll") for (int fn = 0; fn < 4; ++fn)                            \
      acc[fm][fn] = __builtin_amdgcn_mfma_f32_16x16x32_bf16(                    \
          AR[fm], BR[fn], acc[fm][fn], 0, 0, 0);                                \
    __builtin_amdgcn_s_setprio(0);

  // prologue: tiles 0,1 into buf0,buf1 (3 loads each)
  STAGE_A(0, lds);          STAGE_W(0, lds + 4096);
  STAGE_A(1, lds + 12288);  STAGE_W(1, lds + 12288 + 4096);
  asm volatile("s_waitcnt vmcnt(3)" ::: "memory");   // t0 landed; t1 in flight
  __builtin_amdgcn_s_barrier();
  __builtin_amdgcn_sched_barrier(0);

  short8_t af[4], bf[4];

  #pragma unroll 2
  for (int kt = 0; kt < 22; ++kt){
    const ushort* bA = lds + (kt & 1) * 12288;
    const ushort* bB = bA + 4096;
    ushort* nA = lds + (kt & 1) * 12288;       // t+2 has same parity
    RD_A(af); RD_B(bf);
    asm volatile("s_waitcnt lgkmcnt(0)" ::: "memory");  // reads drained...
    __builtin_amdgcn_sched_barrier(0);
    __builtin_amdgcn_s_barrier();                       // ...before anyone overwrites
    __builtin_amdgcn_sched_barrier(0);
    STAGE_A(kt + 2, nA);
    STAGE_W(kt + 2, nA + 4096);
    MM(af, bf);
    asm volatile("s_waitcnt vmcnt(3)" ::: "memory");    // t+1 retired, t+2 in flight
    __builtin_amdgcn_s_barrier();
    __builtin_amdgcn_sched_barrier(0);
  }
  // tile 22 (no staging)
  {
    const ushort* bA = lds;          // 22 & 1 == 0
    const ushort* bB = bA + 4096;
    RD_A(af); RD_B(bf);
    asm volatile("s_waitcnt lgkmcnt(0)" ::: "memory");
    __builtin_amdgcn_sched_barrier(0);
    MM(af, bf);
    asm volatile("s_waitcnt vmcnt(0)" ::: "memory");    // t23 retired
    __builtin_amdgcn_s_barrier();                       // published
    __builtin_amdgcn_sched_barrier(0);
  }
  // tile 23
  {
    const ushort* bA = lds + 12288;
    const ushort* bB = bA + 4096;
    RD_A(af); RD_B(bf);
    asm volatile("s_waitcnt lgkmcnt(0)" ::: "memory");
    __builtin_amdgcn_sched_barrier(0);
    MM(af, bf);
  }
  #undef STAGE_A
  #undef STAGE_W
  #undef RD_A
  #undef RD_B
  #undef MM

  // epilogue: C write (bf16)
  #pragma unroll
  for (int fm = 0; fm < 4; ++fm)
    #pragma unroll
    for (int fn = 0; fn < 4; ++fn)
      #pragma unroll
      for (int r = 0; r < 4; ++r){
        int m = m0 + wr*64 + fm*16 + lg*4 + r;
        int c = n0 + wc*64 + fn*16 + lr;
        Cq[(size_t)m * CQ_ + c] = f2bf(acc[fm][fn][r]);
      }

  // fused column sum-of-squares for q,k columns (n0 < 1536)
  if (bx < 6){
    const int b = m0 >> 13;
    #pragma unroll
    for (int fn = 0; fn < 4; ++fn){
      float s = 0.f;
      #pragma unroll
      for (int fm = 0; fm < 4; ++fm)
        #pragma unroll
        for (int r = 0; r < 4; ++r)
          s = fmaf(acc[fm][fn][r], acc[fm][fn][r], s);
      s += __shfl_xor(s, 16);
      s += __shfl_xor(s, 32);
      if (lg == 0)
        atomicAdd(&norm2[b * 1536 + n0 + wc*64 + fn*16 + lr], s);
    }
  }
}

// ---------------- Gram via MFMA: S_part[kc][bh][d][e] partial sums ----------
// 512 threads (8 waves, 2d x 4e). Pair-packed transposed LDS: dword (np,d) =
// {bf16(n=2np,d), bf16(n=2np+1,d)} -> fragments are plain ds_read_b32.
// Reg-staged double-buffered global loads; all cross-wave sync via __syncthreads.
__global__ __launch_bounds__(512) void gram_mfma(const ushort* __restrict__ Qk,
                                                 float* __restrict__ Sp){
  const int kc = blockIdx.x;      // 16 K-chunks of 512 rows
  const int bh = blockIdx.y;      // 16
  const int b = bh >> 2, h = bh & 3;
  __shared__ __align__(16) uint pk[2][2][3232];   // [buf][mat][np*202 + d], d<192
  const int t = threadIdx.x;
  const int wid = t >> 6, lane = t & 63;
  const int wd = wid >> 2, we = wid & 3;          // wave tile: 96(d) x 48(e)
  const int lr = lane & 15, lg = lane >> 4;

  f32x4 acc[6][3];
  #pragma unroll
  for (int i = 0; i < 6; ++i)
    #pragma unroll
    for (int j = 0; j < 3; ++j)
      acc[i][j] = (f32x4){0.f, 0.f, 0.f, 0.f};

  const uint* gq = (const uint*)Qk + (size_t)b * N_ * 1152;   // dword rows

  uint r0[6], r1[6];
  #define GLOAD(IT)                                                             \
    _Pragma("unroll") for (int u = 0; u < 6; ++u){                              \
      int id = u*512 + t, mat = id/1536, rem = id - mat*1536;                   \
      int np = rem/96, c = rem - np*96;                                         \
      const uint* p = gq + (size_t)(kc*512 + (IT)*32 + 2*np)*1152               \
                         + (mat ? 384 + h*96 : h*96) + c;                       \
      r0[u] = p[0]; r1[u] = p[1152];                                            \
    }
  #define LWRITE(BUF)                                                           \
    _Pragma("unroll") for (int u = 0; u < 6; ++u){                              \
      int id = u*512 + t, mat = id/1536, rem = id - mat*1536;                   \
      int np = rem/96, c = rem - np*96;                                         \
      uint o0 = (r0[u] & 0xFFFFu) | (r1[u] << 16);                              \
      uint o1 = (r0[u] >> 16) | (r1[u] & 0xFFFF0000u);                          \
      *(uint2*)&pk[BUF][mat][np*202 + 2*c] = (uint2){o0, o1};                   \
    }

  GLOAD(0);
  LWRITE(0);
  __syncthreads();

  for (int it = 0; it < 16; ++it){
    const int cur = it & 1;
    if (it < 15) GLOAD(it + 1);     // in flight under compute
    union { uint u[4]; short8_t v; } af[6], bf[3];
    #pragma unroll
    for (int i = 0; i < 6; ++i){
      int d = wd * 96 + i * 16 + lr;
      #pragma unroll
      for (int p = 0; p < 4; ++p)
        af[i].u[p] = pk[cur][0][(lg*4 + p)*202 + d];
    }
    #pragma unroll
    for (int j = 0; j < 3; ++j){
      int e = we * 48 + j * 16 + lr;
      #pragma unroll
      for (int p = 0; p < 4; ++p)
        bf[j].u[p] = pk[cur][1][(lg*4 + p)*202 + e];
    }
    #pragma unroll
    for (int i = 0; i < 6; ++i)
      #pragma unroll
      for (int j = 0; j < 3; ++j)
        acc[i][j] = __builtin_amdgcn_mfma_f32_16x16x32_bf16(af[i].v, bf[j].v, acc[i][j], 0, 0, 0);
    if (it < 15) LWRITE(cur ^ 1);   // opposite buffer: no WAR with current reads
    __syncthreads();
  }
  #undef GLOAD
  #undef LWRITE

  float* base = Sp + (size_t)(kc * 16 + bh) * 192 * 192;
  #pragma unroll
  for (int i = 0; i < 6; ++i)
    #pragma unroll
    for (int j = 0; j < 3; ++j)
      #pragma unroll
      for (int r = 0; r < 4; ++r){
        int d = wd * 96 + i * 16 + lg * 4 + r;
        int e = we * 48 + j * 16 + lr;
        base[(size_t)d * 192 + e] = acc[i][j][r];
      }
}

// ---------------- softmax rows: reduce 16 partial slices + temp + l2 fold ---
__global__ __launch_bounds__(256) void softmax_k(const float* __restrict__ Sp,
                                                 const float* __restrict__ norm2,
                                                 const float* __restrict__ temp,
                                                 ushort* __restrict__ attn){
  const int wid  = blockIdx.x * 4 + (threadIdx.x >> 6);  // row id [0,3072)
  const int lane = threadIdx.x & 63;
  const int bh = wid / 192, d = wid % 192;
  const int b = bh >> 2, h = bh & 3;
  const float nq = sqrtf(norm2[b*1536 + h*192 + d]);
  const float sc = temp[h] / fmaxf(nq, 1e-12f);
  const float* Sr = Sp + ((size_t)bh * 192 + d) * 192;
  float l[3];
  #pragma unroll
  for (int u = 0; u < 3; ++u){
    int e = lane + u * 64;
    float s = 0.f;
    #pragma unroll
    for (int kc = 0; kc < 16; ++kc)
      s += Sr[(size_t)kc * (16*192*192) + e];
    float nk = sqrtf(norm2[b*1536 + 768 + h*192 + e]);
    l[u] = s * sc / fmaxf(nk, 1e-12f);
  }
  float m = fmaxf(l[0], fmaxf(l[1], l[2]));
  #pragma unroll
  for (int off = 32; off; off >>= 1) m = fmaxf(m, __shfl_xor(m, off));
  float p[3], s = 0.f;
  #pragma unroll
  for (int u = 0; u < 3; ++u){ p[u] = expf(l[u] - m); s += p[u]; }
  #pragma unroll
  for (int off = 32; off; off >>= 1) s += __shfl_xor(s, off);
  float inv = 1.f / s;
  ushort* ar = attn + ((size_t)bh * 192 + d) * 192;
  #pragma unroll
  for (int u = 0; u < 3; ++u) ar[lane + u*64] = f2bf(p[u] * inv);
}

// ---------------- out[n][h*192+d] = sum_e V[n][e] * attn[d][e] --------------
__global__ __launch_bounds__(256) void out_gemm(const ushort* __restrict__ Q,
                                                const ushort* __restrict__ attn,
                                                float* __restrict__ out){
  const int bh = blockIdx.y;
  const int b = bh >> 2, h = bh & 3;
  const int n0 = blockIdx.x * 128;
  const int t = threadIdx.x, w = t >> 6, lane = t & 63;
  const int wn = w & 1, wd = w >> 1;
  const int lr = lane & 15, lg = lane >> 4;
  f32x4 acc[4][6];
  #pragma unroll
  for (int i = 0; i < 4; ++i)
    #pragma unroll
    for (int j = 0; j < 6; ++j)
      acc[i][j] = (f32x4){0.f, 0.f, 0.f, 0.f};

  const ushort* Vbase = Q + 1536 + h * 192;
  const ushort* Abase = attn + (size_t)bh * 192 * 192;

  #pragma unroll
  for (int kk = 0; kk < 6; ++kk){
    const int e = kk * 32 + lg * 8;
    short8_t av[4], bv[6];
    #pragma unroll
    for (int f = 0; f < 4; ++f){
      int n = n0 + wn*64 + f*16 + lr;
      av[f] = *(const short8_t*)(Vbase + (size_t)(b*N_ + n) * CQ_ + e);
    }
    #pragma unroll
    for (int f = 0; f < 6; ++f){
      int d = wd*96 + f*16 + lr;
      bv[f] = *(const short8_t*)(Abase + d * 192 + e);
    }
    #pragma unroll
    for (int i = 0; i < 4; ++i)
      #pragma unroll
      for (int j = 0; j < 6; ++j)
        acc[i][j] = __builtin_amdgcn_mfma_f32_16x16x32_bf16(av[i], bv[j], acc[i][j], 0, 0, 0);
  }
  #pragma unroll
  for (int i = 0; i < 4; ++i)
    #pragma unroll
    for (int j = 0; j < 6; ++j)
      #pragma unroll
      for (int r = 0; r < 4; ++r){
        int n = n0 + wn*64 + i*16 + lg*4 + r;
        int c = h*192 + wd*96 + j*16 + lr;
        out[(size_t)(b*N_ + n) * 768 + c] = acc[i][j][r];
      }
}

// ---------------------------------------------------------------------------
extern "C" void kernel_launch(void* const* d_in, const int* in_sizes, int n_in,
                              void* d_out, int out_size, void* d_ws, size_t ws_size,
                              hipStream_t stream){
  const float* x    = (const float*)d_in[0];
  const float* Wq   = (const float*)d_in[1];
  const float* temp = (const float*)d_in[2];
  float* out = (float*)d_out;
  char* ws = (char*)d_ws;

  // workspace layout (bytes) — S_part/attn overlay xb (dead after gemm_qkvv)
  ushort* xb    = (ushort*)(ws + 0);          //  50,331,648 (dead after gemm)
  float*  S_part= (float*)(ws + 0);           //  37,748,736 (16 slices)
  ushort* attn  = (ushort*)(ws + 37748736);   //   1,179,648
  ushort* Wb    = (ushort*)(ws + 50331648);   //   3,538,944
  ushort* qkvv  = (ushort*)(ws + 53870592);   // 150,994,944
  float*  norm2 = (float*)(ws + 204865536);   //      24,576

  static_assert(sizeof(ushort) == 2, "");
  hipFuncSetAttribute((const void*)gemm_qkvv,
                      hipFuncAttributeMaxDynamicSharedMemorySize, 49152);

  cvt_all<<<26304, 256, 0, stream>>>(x, xb, Wq, Wb, norm2);

  gemm_qkvv<<<2304, 512, 49152, stream>>>(xb, Wb, qkvv, norm2);

  gram_mfma<<<dim3(16, 16), 512, 0, stream>>>(qkvv, S_part);
  softmax_k<<<768, 256, 0, stream>>>(S_part, norm2, temp, attn);
  out_gemm<<<dim3(64, 16), 256, 0, stream>>>(qkvv, attn, out);
}

// Round 17
// 232.871 us; speedup vs baseline: 1.0274x; 1.0241x over previous
//
#include <hip/hip_runtime.h>
#include <hip/hip_bf16.h>
#include <cstddef>
#include <cstdint>

#define B_   4
#define N_   8192
#define C_   768
#define H_   4
#define D_   192
#define CQ_  2304   // 3*C
#define M_   32768  // B*N

typedef __attribute__((ext_vector_type(8))) short short8_t;
typedef __attribute__((ext_vector_type(4))) float f32x4;

typedef const __attribute__((address_space(1))) uint gq_uint;
typedef __attribute__((address_space(3))) uint lds_uint;

__device__ inline ushort f2bf(float f){
  uint u = __float_as_uint(f);
  u += 0x7FFFu + ((u >> 16) & 1u);   // RNE; inputs are finite
  return (ushort)(u >> 16);
}
__device__ inline float bf2f(ushort u){ return __uint_as_float(((uint)u) << 16); }

// ---------------- fused fp32->bf16 for x and W + norm2 zeroing (1 dispatch) --
__global__ __launch_bounds__(256) void cvt_all(const float* __restrict__ x,
                                               ushort* __restrict__ xb,
                                               const float* __restrict__ Wq,
                                               ushort* __restrict__ Wb,
                                               float* __restrict__ norm2){
  int i = blockIdx.x * 256 + threadIdx.x;
  if (i < 6144) norm2[i] = 0.f;
  if (i < 6291456){
    float4 v = ((const float4*)x)[i];
    ushort4 o;
    o.x = f2bf(v.x); o.y = f2bf(v.y); o.z = f2bf(v.z); o.w = f2bf(v.w);
    ((ushort4*)xb)[i] = o;
  } else if (i < 6291456 + 442368){
    int j = i - 6291456;
    float4 v = ((const float4*)Wq)[j];
    ushort4 o;
    o.x = f2bf(v.x); o.y = f2bf(v.y); o.z = f2bf(v.z); o.w = f2bf(v.w);
    ((ushort4*)Wb)[j] = o;
  }
}

// ---------------- QKV projection: [32768,768] x [2304,768]^T -> bf16 [32768,2304]
// R11-verified schedule: 256x256 tile, BK=64, 8 waves (2Mx4N). 4-phase K-tile:
// per phase {ds_reads, stage 1 half-tile, vmcnt(4)+barrier+lgkmcnt(0), 16 MFMA}.
// BK=64 (128B rows) is conflict-free; BK=32 (64B rows) showed a constant
// 1.4e7 SQ_LDS_BANK_CONFLICT across all swizzles (R3/R15/R16) — geometry-
// intrinsic, so the 2-blocks/CU variant loses despite 2x occupancy.
// Fused: column sum-of-squares for q,k (bx < 6).
__global__ __launch_bounds__(512, 2) void gemm_qkvv(const ushort* __restrict__ A,
                                                    const ushort* __restrict__ W,
                                                    ushort* __restrict__ Cq,
                                                    float* __restrict__ norm2){
  extern __shared__ ushort lds[];   // 2 buf x (A 16384 + B 16384) ushorts = 128 KiB
  const int t = threadIdx.x;
  // XCD-aware swizzle: 1152 = 8 * 144
  const int bid = blockIdx.x;
  const int wg  = (bid & 7) * 144 + (bid >> 3);
  const int by = wg / 9, bx = wg % 9;
  const int m0 = by * 256, n0 = bx * 256;
  const int wid = t >> 6, lane = t & 63;
  const int wm = wid >> 2, wn = wid & 3;
  const int lr = lane & 15, lg = lane >> 4;
  // staging lane geometry: 8 rows/wave/inst, slot pre-swizzled (involution)
  const int srow  = lane >> 3;
  const int sslot = (lane & 7) ^ srow;

  // acc[i][j]: global row = m0 + (i>>2)*128 + wm*64 + (i&3)*16, col = n0 + (j>>1)*128 + wn*32 + (j&1)*16
  f32x4 acc[8][4];
  #pragma unroll
  for (int i = 0; i < 8; ++i)
    #pragma unroll
    for (int j = 0; j < 4; ++j)
      acc[i][j] = (f32x4){0.f, 0.f, 0.f, 0.f};

  #define STAGE_HALF(GPTR, G0, KT, LBASE, HALF)                                 \
    do {                                                                        \
      _Pragma("unroll")                                                         \
      for (int rnd_ = 0; rnd_ < 2; ++rnd_){                                     \
        const int row_ = (HALF) * 128 + rnd_ * 64 + wid * 8;                    \
        __builtin_amdgcn_global_load_lds(                                       \
            (gq_uint*)(const void*)((GPTR) + (size_t)((G0) + row_ + srow) * 768 \
                                    + (KT) * 64 + sslot * 8),                   \
            (lds_uint*)(void*)((LBASE) + row_ * 64), 16, 0, 0);                 \
      }                                                                         \
    } while (0)

  #define RD_A(DST, MH)                                                         \
    _Pragma("unroll") for (int kk = 0; kk < 2; ++kk){                           \
      const int sl = ((kk * 4 + lg) ^ (lr & 7)) * 8;                            \
      _Pragma("unroll") for (int fm = 0; fm < 4; ++fm)                          \
        DST[kk][fm] = *(const short8_t*)(bA + ((MH)*128 + wm*64 + fm*16 + lr)*64 + sl); }

  #define RD_B(DST, NH)                                                         \
    _Pragma("unroll") for (int kk = 0; kk < 2; ++kk){                           \
      const int sl = ((kk * 4 + lg) ^ (lr & 7)) * 8;                            \
      _Pragma("unroll") for (int fl = 0; fl < 2; ++fl)                          \
        DST[kk][fl] = *(const short8_t*)(bB + ((NH)*128 + wn*32 + fl*16 + lr)*64 + sl); }

  #define MM(AR, BR, IO, JO)                                                    \
    __builtin_amdgcn_s_setprio(1);                                              \
    _Pragma("unroll") for (int kk = 0; kk < 2; ++kk)                            \
    _Pragma("unroll") for (int fm = 0; fm < 4; ++fm)                            \
    _Pragma("unroll") for (int fl = 0; fl < 2; ++fl)                            \
      acc[(IO)+fm][(JO)+fl] = __builtin_amdgcn_mfma_f32_16x16x32_bf16(          \
          AR[kk][fm], BR[kk][fl], acc[(IO)+fm][(JO)+fl], 0, 0, 0);              \
    __builtin_amdgcn_s_setprio(0);

  #define WAITP(N)                                                              \
    asm volatile("s_waitcnt vmcnt(" #N ")" ::: "memory");                       \
    __builtin_amdgcn_s_barrier();                                               \
    asm volatile("s_waitcnt lgkmcnt(0)" ::: "memory");                          \
    __builtin_amdgcn_sched_barrier(0);

  // prologue: tile 0 fully staged into buf0
  STAGE_HALF(A, m0, 0, lds,         0);
  STAGE_HALF(A, m0, 0, lds,         1);
  STAGE_HALF(W, n0, 0, lds + 16384, 0);
  STAGE_HALF(W, n0, 0, lds + 16384, 1);
  asm volatile("s_waitcnt vmcnt(0)" ::: "memory");
  __builtin_amdgcn_s_barrier();
  __builtin_amdgcn_sched_barrier(0);

  short8_t a0[2][4], a1[2][4], bf0[2][2], bf1[2][2];

  #pragma unroll 2
  for (int kt = 0; kt < 11; ++kt){
    const ushort* bA = lds + (kt & 1) * 32768;
    const ushort* bB = bA + 16384;
    ushort* nA = lds + ((kt + 1) & 1) * 32768;
    ushort* nB = nA + 16384;
    // Q0 (mh0,nh0): reads A0(8)+B0(4); stage next A0
    RD_A(a0, 0); RD_B(bf0, 0);
    STAGE_HALF(A, m0, kt + 1, nA, 0);
    WAITP(4);
    MM(a0, bf0, 0, 0);
    // Q1 (mh1,nh0): reads A1(8); stage next B0
    RD_A(a1, 1);
    STAGE_HALF(W, n0, kt + 1, nB, 0);
    WAITP(4);
    MM(a1, bf0, 4, 0);
    // Q2 (mh1,nh1): reads B1(4); stage next A1
    RD_B(bf1, 1);
    STAGE_HALF(A, m0, kt + 1, nA, 1);
    WAITP(4);
    MM(a1, bf1, 4, 2);
    // Q3 (mh0,nh1): no reads; stage next B1
    STAGE_HALF(W, n0, kt + 1, nB, 1);
    WAITP(4);
    MM(a0, bf1, 0, 2);
  }
  // tile 11 (no staging; tightened waits — each WAITP includes the barrier)
  {
    const ushort* bA = lds + 32768;
    const ushort* bB = bA + 16384;
    RD_A(a0, 0); RD_B(bf0, 0);
    WAITP(2);
    MM(a0, bf0, 0, 0);
    RD_A(a1, 1);
    WAITP(0);
    MM(a1, bf0, 4, 0);
    RD_B(bf1, 1);
    asm volatile("s_waitcnt lgkmcnt(0)" ::: "memory");
    __builtin_amdgcn_sched_barrier(0);
    MM(a1, bf1, 4, 2);
    MM(a0, bf1, 0, 2);
  }
  #undef STAGE_HALF
  #undef RD_A
  #undef RD_B
  #undef MM
  #undef WAITP

  // epilogue: C write (bf16)
  #pragma unroll
  for (int i = 0; i < 8; ++i)
    #pragma unroll
    for (int j = 0; j < 4; ++j)
      #pragma unroll
      for (int r = 0; r < 4; ++r){
        int m = m0 + (i >> 2) * 128 + wm * 64 + (i & 3) * 16 + lg * 4 + r;
        int c = n0 + (j >> 1) * 128 + wn * 32 + (j & 1) * 16 + lr;
        Cq[(size_t)m * CQ_ + c] = f2bf(acc[i][j][r]);
      }

  // fused column sum-of-squares for q,k columns (n0 < 1536)
  if (bx < 6){
    const int b = m0 >> 13;
    #pragma unroll
    for (int j = 0; j < 4; ++j){
      float s = 0.f;
      #pragma unroll
      for (int i = 0; i < 8; ++i)
        #pragma unroll
        for (int r = 0; r < 4; ++r)
          s = fmaf(acc[i][j][r], acc[i][j][r], s);
      s += __shfl_xor(s, 16);
      s += __shfl_xor(s, 32);
      if (lg == 0)
        atomicAdd(&norm2[b * 1536 + n0 + (j >> 1) * 128 + wn * 32 + (j & 1) * 16 + lr], s);
    }
  }
}

// ---------------- Gram via MFMA: S_part[kc][bh][d][e] partial sums ----------
// 512 threads (8 waves, 2d x 4e). Pair-packed transposed LDS: dword (np,d) =
// {bf16(n=2np,d), bf16(n=2np+1,d)} -> fragments are plain ds_read_b32.
// Reg-staged double-buffered global loads; all cross-wave sync via __syncthreads.
__global__ __launch_bounds__(512) void gram_mfma(const ushort* __restrict__ Qk,
                                                 float* __restrict__ Sp){
  const int kc = blockIdx.x;      // 16 K-chunks of 512 rows
  const int bh = blockIdx.y;      // 16
  const int b = bh >> 2, h = bh & 3;
  __shared__ __align__(16) uint pk[2][2][3232];   // [buf][mat][np*202 + d], d<192
  const int t = threadIdx.x;
  const int wid = t >> 6, lane = t & 63;
  const int wd = wid >> 2, we = wid & 3;          // wave tile: 96(d) x 48(e)
  const int lr = lane & 15, lg = lane >> 4;

  f32x4 acc[6][3];
  #pragma unroll
  for (int i = 0; i < 6; ++i)
    #pragma unroll
    for (int j = 0; j < 3; ++j)
      acc[i][j] = (f32x4){0.f, 0.f, 0.f, 0.f};

  const uint* gq = (const uint*)Qk + (size_t)b * N_ * 1152;   // dword rows

  uint r0[6], r1[6];
  #define GLOAD(IT)                                                             \
    _Pragma("unroll") for (int u = 0; u < 6; ++u){                              \
      int id = u*512 + t, mat = id/1536, rem = id - mat*1536;                   \
      int np = rem/96, c = rem - np*96;                                         \
      const uint* p = gq + (size_t)(kc*512 + (IT)*32 + 2*np)*1152               \
                         + (mat ? 384 + h*96 : h*96) + c;                       \
      r0[u] = p[0]; r1[u] = p[1152];                                            \
    }
  #define LWRITE(BUF)                                                           \
    _Pragma("unroll") for (int u = 0; u < 6; ++u){                              \
      int id = u*512 + t, mat = id/1536, rem = id - mat*1536;                   \
      int np = rem/96, c = rem - np*96;                                         \
      uint o0 = (r0[u] & 0xFFFFu) | (r1[u] << 16);                              \
      uint o1 = (r0[u] >> 16) | (r1[u] & 0xFFFF0000u);                          \
      *(uint2*)&pk[BUF][mat][np*202 + 2*c] = (uint2){o0, o1};                   \
    }

  GLOAD(0);
  LWRITE(0);
  __syncthreads();

  for (int it = 0; it < 16; ++it){
    const int cur = it & 1;
    if (it < 15) GLOAD(it + 1);     // in flight under compute
    union { uint u[4]; short8_t v; } af[6], bf[3];
    #pragma unroll
    for (int i = 0; i < 6; ++i){
      int d = wd * 96 + i * 16 + lr;
      #pragma unroll
      for (int p = 0; p < 4; ++p)
        af[i].u[p] = pk[cur][0][(lg*4 + p)*202 + d];
    }
    #pragma unroll
    for (int j = 0; j < 3; ++j){
      int e = we * 48 + j * 16 + lr;
      #pragma unroll
      for (int p = 0; p < 4; ++p)
        bf[j].u[p] = pk[cur][1][(lg*4 + p)*202 + e];
    }
    #pragma unroll
    for (int i = 0; i < 6; ++i)
      #pragma unroll
      for (int j = 0; j < 3; ++j)
        acc[i][j] = __builtin_amdgcn_mfma_f32_16x16x32_bf16(af[i].v, bf[j].v, acc[i][j], 0, 0, 0);
    if (it < 15) LWRITE(cur ^ 1);   // opposite buffer: no WAR with current reads
    __syncthreads();
  }
  #undef GLOAD
  #undef LWRITE

  float* base = Sp + (size_t)(kc * 16 + bh) * 192 * 192;
  #pragma unroll
  for (int i = 0; i < 6; ++i)
    #pragma unroll
    for (int j = 0; j < 3; ++j)
      #pragma unroll
      for (int r = 0; r < 4; ++r){
        int d = wd * 96 + i * 16 + lg * 4 + r;
        int e = we * 48 + j * 16 + lr;
        base[(size_t)d * 192 + e] = acc[i][j][r];
      }
}

// ---------------- softmax rows: reduce 16 partial slices + temp + l2 fold ---
__global__ __launch_bounds__(256) void softmax_k(const float* __restrict__ Sp,
                                                 const float* __restrict__ norm2,
                                                 const float* __restrict__ temp,
                                                 ushort* __restrict__ attn){
  const int wid  = blockIdx.x * 4 + (threadIdx.x >> 6);  // row id [0,3072)
  const int lane = threadIdx.x & 63;
  const int bh = wid / 192, d = wid % 192;
  const int b = bh >> 2, h = bh & 3;
  const float nq = sqrtf(norm2[b*1536 + h*192 + d]);
  const float sc = temp[h] / fmaxf(nq, 1e-12f);
  const float* Sr = Sp + ((size_t)bh * 192 + d) * 192;
  float l[3];
  #pragma unroll
  for (int u = 0; u < 3; ++u){
    int e = lane + u * 64;
    float s = 0.f;
    #pragma unroll
    for (int kc = 0; kc < 16; ++kc)
      s += Sr[(size_t)kc * (16*192*192) + e];
    float nk = sqrtf(norm2[b*1536 + 768 + h*192 + e]);
    l[u] = s * sc / fmaxf(nk, 1e-12f);
  }
  float m = fmaxf(l[0], fmaxf(l[1], l[2]));
  #pragma unroll
  for (int off = 32; off; off >>= 1) m = fmaxf(m, __shfl_xor(m, off));
  float p[3], s = 0.f;
  #pragma unroll
  for (int u = 0; u < 3; ++u){ p[u] = expf(l[u] - m); s += p[u]; }
  #pragma unroll
  for (int off = 32; off; off >>= 1) s += __shfl_xor(s, off);
  float inv = 1.f / s;
  ushort* ar = attn + ((size_t)bh * 192 + d) * 192;
  #pragma unroll
  for (int u = 0; u < 3; ++u) ar[lane + u*64] = f2bf(p[u] * inv);
}

// ---------------- out[n][h*192+d] = sum_e V[n][e] * attn[d][e] --------------
__global__ __launch_bounds__(256) void out_gemm(const ushort* __restrict__ Q,
                                                const ushort* __restrict__ attn,
                                                float* __restrict__ out){
  const int bh = blockIdx.y;
  const int b = bh >> 2, h = bh & 3;
  const int n0 = blockIdx.x * 128;
  const int t = threadIdx.x, w = t >> 6, lane = t & 63;
  const int wn = w & 1, wd = w >> 1;
  const int lr = lane & 15, lg = lane >> 4;
  f32x4 acc[4][6];
  #pragma unroll
  for (int i = 0; i < 4; ++i)
    #pragma unroll
    for (int j = 0; j < 6; ++j)
      acc[i][j] = (f32x4){0.f, 0.f, 0.f, 0.f};

  const ushort* Vbase = Q + 1536 + h * 192;
  const ushort* Abase = attn + (size_t)bh * 192 * 192;

  #pragma unroll
  for (int kk = 0; kk < 6; ++kk){
    const int e = kk * 32 + lg * 8;
    short8_t av[4], bv[6];
    #pragma unroll
    for (int f = 0; f < 4; ++f){
      int n = n0 + wn*64 + f*16 + lr;
      av[f] = *(const short8_t*)(Vbase + (size_t)(b*N_ + n) * CQ_ + e);
    }
    #pragma unroll
    for (int f = 0; f < 6; ++f){
      int d = wd*96 + f*16 + lr;
      bv[f] = *(const short8_t*)(Abase + d * 192 + e);
    }
    #pragma unroll
    for (int i = 0; i < 4; ++i)
      #pragma unroll
      for (int j = 0; j < 6; ++j)
        acc[i][j] = __builtin_amdgcn_mfma_f32_16x16x32_bf16(av[i], bv[j], acc[i][j], 0, 0, 0);
  }
  #pragma unroll
  for (int i = 0; i < 4; ++i)
    #pragma unroll
    for (int j = 0; j < 6; ++j)
      #pragma unroll
      for (int r = 0; r < 4; ++r){
        int n = n0 + wn*64 + i*16 + lg*4 + r;
        int c = h*192 + wd*96 + j*16 + lr;
        out[(size_t)(b*N_ + n) * 768 + c] = acc[i][j][r];
      }
}

// ---------------------------------------------------------------------------
extern "C" void kernel_launch(void* const* d_in, const int* in_sizes, int n_in,
                              void* d_out, int out_size, void* d_ws, size_t ws_size,
                              hipStream_t stream){
  const float* x    = (const float*)d_in[0];
  const float* Wq   = (const float*)d_in[1];
  const float* temp = (const float*)d_in[2];
  float* out = (float*)d_out;
  char* ws = (char*)d_ws;

  // workspace layout (bytes) — S_part/attn overlay xb (dead after gemm_qkvv)
  ushort* xb    = (ushort*)(ws + 0);          //  50,331,648 (dead after gemm)
  float*  S_part= (float*)(ws + 0);           //  37,748,736 (16 slices)
  ushort* attn  = (ushort*)(ws + 37748736);   //   1,179,648
  ushort* Wb    = (ushort*)(ws + 50331648);   //   3,538,944
  ushort* qkvv  = (ushort*)(ws + 53870592);   // 150,994,944
  float*  norm2 = (float*)(ws + 204865536);   //      24,576

  static_assert(sizeof(ushort) == 2, "");
  hipFuncSetAttribute((const void*)gemm_qkvv,
                      hipFuncAttributeMaxDynamicSharedMemorySize, 131072);

  cvt_all<<<26304, 256, 0, stream>>>(x, xb, Wq, Wb, norm2);

  gemm_qkvv<<<1152, 512, 131072, stream>>>(xb, Wb, qkvv, norm2);

  gram_mfma<<<dim3(16, 16), 512, 0, stream>>>(qkvv, S_part);
  softmax_k<<<768, 256, 0, stream>>>(S_part, norm2, temp, attn);
  out_gemm<<<dim3(64, 16), 256, 0, stream>>>(qkvv, attn, out);
}

// Round 18
// 232.609 us; speedup vs baseline: 1.0285x; 1.0011x over previous
//
#include <hip/hip_runtime.h>
#include <hip/hip_bf16.h>
#include <cstddef>
#include <cstdint>

#define B_   4
#define N_   8192
#define C_   768
#define H_   4
#define D_   192
#define CQ_  2304   // 3*C
#define M_   32768  // B*N

typedef __attribute__((ext_vector_type(8))) short short8_t;
typedef __attribute__((ext_vector_type(4))) float f32x4;

typedef const __attribute__((address_space(1))) uint gq_uint;
typedef __attribute__((address_space(3))) uint lds_uint;

__device__ inline ushort f2bf(float f){
  uint u = __float_as_uint(f);
  u += 0x7FFFu + ((u >> 16) & 1u);   // RNE; inputs are finite
  return (ushort)(u >> 16);
}
__device__ inline float bf2f(ushort u){ return __uint_as_float(((uint)u) << 16); }

// ---------------- fused fp32->bf16 for x and W + norm2 zeroing (1 dispatch) --
__global__ __launch_bounds__(256) void cvt_all(const float* __restrict__ x,
                                               ushort* __restrict__ xb,
                                               const float* __restrict__ Wq,
                                               ushort* __restrict__ Wb,
                                               float* __restrict__ norm2){
  int i = blockIdx.x * 256 + threadIdx.x;
  if (i < 6144) norm2[i] = 0.f;
  if (i < 6291456){
    float4 v = ((const float4*)x)[i];
    ushort4 o;
    o.x = f2bf(v.x); o.y = f2bf(v.y); o.z = f2bf(v.z); o.w = f2bf(v.w);
    ((ushort4*)xb)[i] = o;
  } else if (i < 6291456 + 442368){
    int j = i - 6291456;
    float4 v = ((const float4*)Wq)[j];
    ushort4 o;
    o.x = f2bf(v.x); o.y = f2bf(v.y); o.z = f2bf(v.z); o.w = f2bf(v.w);
    ((ushort4*)Wb)[j] = o;
  }
}

// ---------------- QKV projection: [32768,768] x [2304,768]^T -> bf16 [32768,2304]
// 128x128 tile, BK=64, 4 waves (2Mx2N, 64x64 each), LDS 64KiB -> 2 blocks/CU.
// Same conflict-free 128B-row swizzle as R11 (key = row&7); R4/R11-proven
// 2-barrier K-tile: {16 ds_reads; lgkm0+bar; stage t+2 -> cur buf (8 gl_lds);
// 32 MFMA; vmcnt(8)+bar}. Bet: 2 independent blocks/CU cover each other's
// barrier stalls (m114 overlap). Fused colsq for q,k (bx < 12).
__global__ __launch_bounds__(256, 2) void gemm_qkvv(const ushort* __restrict__ A,
                                                    const ushort* __restrict__ W,
                                                    ushort* __restrict__ Cq,
                                                    float* __restrict__ norm2){
  extern __shared__ ushort lds[];   // 2 buf x (A 128x64 + B 128x64) = 65536 B
  const int t = threadIdx.x;
  // XCD-aware swizzle: 4608 = 8 * 576
  const int bid = blockIdx.x;
  const int wg  = (bid & 7) * 576 + (bid >> 3);
  const int by = wg / 18, bx = wg % 18;
  const int m0 = by * 128, n0 = bx * 128;
  const int wid = t >> 6, lane = t & 63;
  const int wm = wid >> 1, wn = wid & 1;        // wave tile 64(M) x 64(N)
  const int lr = lane & 15, lg = lane >> 4;
  // staging lane geometry (identical to R11): 8 rows/inst, key(row)=row&7=srow
  const int srow  = lane >> 3;
  const int sslot = (lane & 7) ^ srow;

  f32x4 acc[4][4];
  #pragma unroll
  for (int i = 0; i < 4; ++i)
    #pragma unroll
    for (int j = 0; j < 4; ++j)
      acc[i][j] = (f32x4){0.f, 0.f, 0.f, 0.f};

  // stage one 128x64 matrix: 4 gl_lds per wave (wave wid covers rows wid*32..+32)
  #define STAGE_M(GPTR, G0, KT, LBASE)                                          \
    _Pragma("unroll")                                                           \
    for (int rnd_ = 0; rnd_ < 4; ++rnd_){                                       \
      const int row_ = wid * 32 + rnd_ * 8;                                     \
      __builtin_amdgcn_global_load_lds(                                         \
          (gq_uint*)(const void*)((GPTR) + (size_t)((G0) + row_ + srow) * 768   \
                                  + (KT) * 64 + sslot * 8),                     \
          (lds_uint*)(void*)((LBASE) + row_ * 64), 16, 0, 0);                   \
    }

  #define RD_A(DST)                                                             \
    _Pragma("unroll") for (int kk = 0; kk < 2; ++kk){                           \
      const int sl = ((kk * 4 + lg) ^ (lr & 7)) * 8;                            \
      _Pragma("unroll") for (int fm = 0; fm < 4; ++fm)                          \
        DST[kk][fm] = *(const short8_t*)(bA + (wm*64 + fm*16 + lr)*64 + sl); }

  #define RD_B(DST)                                                             \
    _Pragma("unroll") for (int kk = 0; kk < 2; ++kk){                           \
      const int sl = ((kk * 4 + lg) ^ (lr & 7)) * 8;                            \
      _Pragma("unroll") for (int fn = 0; fn < 4; ++fn)                          \
        DST[kk][fn] = *(const short8_t*)(bB + (wn*64 + fn*16 + lr)*64 + sl); }

  #define MM(AR, BR)                                                            \
    __builtin_amdgcn_s_setprio(1);                                              \
    _Pragma("unroll") for (int kk = 0; kk < 2; ++kk)                            \
    _Pragma("unroll") for (int fm = 0; fm < 4; ++fm)                            \
    _Pragma("unroll") for (int fn = 0; fn < 4; ++fn)                            \
      acc[fm][fn] = __builtin_amdgcn_mfma_f32_16x16x32_bf16(                    \
          AR[kk][fm], BR[kk][fn], acc[fm][fn], 0, 0, 0);                        \
    __builtin_amdgcn_s_setprio(0);

  // prologue: t0 -> buf0, t1 -> buf1; wait t0 (t1's 8 stay in flight)
  STAGE_M(A, m0, 0, lds);
  STAGE_M(W, n0, 0, lds + 8192);
  STAGE_M(A, m0, 1, lds + 16384);
  STAGE_M(W, n0, 1, lds + 16384 + 8192);
  asm volatile("s_waitcnt vmcnt(8)" ::: "memory");
  __builtin_amdgcn_s_barrier();
  __builtin_amdgcn_sched_barrier(0);

  short8_t af[2][4], bf[2][4];

  #pragma unroll 2
  for (int kt = 0; kt < 10; ++kt){
    const ushort* bA = lds + (kt & 1) * 16384;
    const ushort* bB = bA + 8192;
    ushort* nb = lds + (kt & 1) * 16384;        // t+2 has same parity
    RD_A(af); RD_B(bf);
    asm volatile("s_waitcnt lgkmcnt(0)" ::: "memory");  // own reads drained...
    __builtin_amdgcn_sched_barrier(0);
    __builtin_amdgcn_s_barrier();                       // ...all waves done reading
    __builtin_amdgcn_sched_barrier(0);
    STAGE_M(A, m0, kt + 2, nb);
    STAGE_M(W, n0, kt + 2, nb + 8192);
    MM(af, bf);
    asm volatile("s_waitcnt vmcnt(8)" ::: "memory");    // t+1 retired, t+2 in flight
    __builtin_amdgcn_s_barrier();                       // published
    __builtin_amdgcn_sched_barrier(0);
  }
  // tile 10 (buf0; no staging)
  {
    const ushort* bA = lds;
    const ushort* bB = bA + 8192;
    RD_A(af); RD_B(bf);
    asm volatile("s_waitcnt lgkmcnt(0)" ::: "memory");
    __builtin_amdgcn_sched_barrier(0);
    MM(af, bf);
    asm volatile("s_waitcnt vmcnt(0)" ::: "memory");    // t11 retired...
    __builtin_amdgcn_s_barrier();                       // ...and published
    __builtin_amdgcn_sched_barrier(0);
  }
  // tile 11 (buf1)
  {
    const ushort* bA = lds + 16384;
    const ushort* bB = bA + 8192;
    RD_A(af); RD_B(bf);
    asm volatile("s_waitcnt lgkmcnt(0)" ::: "memory");
    __builtin_amdgcn_sched_barrier(0);
    MM(af, bf);
  }
  #undef STAGE_M
  #undef RD_A
  #undef RD_B
  #undef MM

  // epilogue: C write (bf16)
  #pragma unroll
  for (int fm = 0; fm < 4; ++fm)
    #pragma unroll
    for (int fn = 0; fn < 4; ++fn)
      #pragma unroll
      for (int r = 0; r < 4; ++r){
        int m = m0 + wm*64 + fm*16 + lg*4 + r;
        int c = n0 + wn*64 + fn*16 + lr;
        Cq[(size_t)m * CQ_ + c] = f2bf(acc[fm][fn][r]);
      }

  // fused column sum-of-squares for q,k columns (n0 < 1536)
  if (bx < 12){
    const int b = m0 >> 13;
    #pragma unroll
    for (int fn = 0; fn < 4; ++fn){
      float s = 0.f;
      #pragma unroll
      for (int fm = 0; fm < 4; ++fm)
        #pragma unroll
        for (int r = 0; r < 4; ++r)
          s = fmaf(acc[fm][fn][r], acc[fm][fn][r], s);
      s += __shfl_xor(s, 16);
      s += __shfl_xor(s, 32);
      if (lg == 0)
        atomicAdd(&norm2[b * 1536 + n0 + wn*64 + fn*16 + lr], s);
    }
  }
}

// ---------------- Gram via MFMA: S_part[kc][bh][d][e] partial sums ----------
// 512 threads (8 waves, 2d x 4e). Pair-packed transposed LDS: dword (np,d) =
// {bf16(n=2np,d), bf16(n=2np+1,d)} -> fragments are plain ds_read_b32.
// Reg-staged double-buffered global loads; all cross-wave sync via __syncthreads.
__global__ __launch_bounds__(512) void gram_mfma(const ushort* __restrict__ Qk,
                                                 float* __restrict__ Sp){
  const int kc = blockIdx.x;      // 16 K-chunks of 512 rows
  const int bh = blockIdx.y;      // 16
  const int b = bh >> 2, h = bh & 3;
  __shared__ __align__(16) uint pk[2][2][3232];   // [buf][mat][np*202 + d], d<192
  const int t = threadIdx.x;
  const int wid = t >> 6, lane = t & 63;
  const int wd = wid >> 2, we = wid & 3;          // wave tile: 96(d) x 48(e)
  const int lr = lane & 15, lg = lane >> 4;

  f32x4 acc[6][3];
  #pragma unroll
  for (int i = 0; i < 6; ++i)
    #pragma unroll
    for (int j = 0; j < 3; ++j)
      acc[i][j] = (f32x4){0.f, 0.f, 0.f, 0.f};

  const uint* gq = (const uint*)Qk + (size_t)b * N_ * 1152;   // dword rows

  uint r0[6], r1[6];
  #define GLOAD(IT)                                                             \
    _Pragma("unroll") for (int u = 0; u < 6; ++u){                              \
      int id = u*512 + t, mat = id/1536, rem = id - mat*1536;                   \
      int np = rem/96, c = rem - np*96;                                         \
      const uint* p = gq + (size_t)(kc*512 + (IT)*32 + 2*np)*1152               \
                         + (mat ? 384 + h*96 : h*96) + c;                       \
      r0[u] = p[0]; r1[u] = p[1152];                                            \
    }
  #define LWRITE(BUF)                                                           \
    _Pragma("unroll") for (int u = 0; u < 6; ++u){                              \
      int id = u*512 + t, mat = id/1536, rem = id - mat*1536;                   \
      int np = rem/96, c = rem - np*96;                                         \
      uint o0 = (r0[u] & 0xFFFFu) | (r1[u] << 16);                              \
      uint o1 = (r0[u] >> 16) | (r1[u] & 0xFFFF0000u);                          \
      *(uint2*)&pk[BUF][mat][np*202 + 2*c] = (uint2){o0, o1};                   \
    }

  GLOAD(0);
  LWRITE(0);
  __syncthreads();

  for (int it = 0; it < 16; ++it){
    const int cur = it & 1;
    if (it < 15) GLOAD(it + 1);     // in flight under compute
    union { uint u[4]; short8_t v; } af[6], bf[3];
    #pragma unroll
    for (int i = 0; i < 6; ++i){
      int d = wd * 96 + i * 16 + lr;
      #pragma unroll
      for (int p = 0; p < 4; ++p)
        af[i].u[p] = pk[cur][0][(lg*4 + p)*202 + d];
    }
    #pragma unroll
    for (int j = 0; j < 3; ++j){
      int e = we * 48 + j * 16 + lr;
      #pragma unroll
      for (int p = 0; p < 4; ++p)
        bf[j].u[p] = pk[cur][1][(lg*4 + p)*202 + e];
    }
    #pragma unroll
    for (int i = 0; i < 6; ++i)
      #pragma unroll
      for (int j = 0; j < 3; ++j)
        acc[i][j] = __builtin_amdgcn_mfma_f32_16x16x32_bf16(af[i].v, bf[j].v, acc[i][j], 0, 0, 0);
    if (it < 15) LWRITE(cur ^ 1);   // opposite buffer: no WAR with current reads
    __syncthreads();
  }
  #undef GLOAD
  #undef LWRITE

  float* base = Sp + (size_t)(kc * 16 + bh) * 192 * 192;
  #pragma unroll
  for (int i = 0; i < 6; ++i)
    #pragma unroll
    for (int j = 0; j < 3; ++j)
      #pragma unroll
      for (int r = 0; r < 4; ++r){
        int d = wd * 96 + i * 16 + lg * 4 + r;
        int e = we * 48 + j * 16 + lr;
        base[(size_t)d * 192 + e] = acc[i][j][r];
      }
}

// ---------------- softmax rows: reduce 16 partial slices + temp + l2 fold ---
__global__ __launch_bounds__(256) void softmax_k(const float* __restrict__ Sp,
                                                 const float* __restrict__ norm2,
                                                 const float* __restrict__ temp,
                                                 ushort* __restrict__ attn){
  const int wid  = blockIdx.x * 4 + (threadIdx.x >> 6);  // row id [0,3072)
  const int lane = threadIdx.x & 63;
  const int bh = wid / 192, d = wid % 192;
  const int b = bh >> 2, h = bh & 3;
  const float nq = sqrtf(norm2[b*1536 + h*192 + d]);
  const float sc = temp[h] / fmaxf(nq, 1e-12f);
  const float* Sr = Sp + ((size_t)bh * 192 + d) * 192;
  float l[3];
  #pragma unroll
  for (int u = 0; u < 3; ++u){
    int e = lane + u * 64;
    float s = 0.f;
    #pragma unroll
    for (int kc = 0; kc < 16; ++kc)
      s += Sr[(size_t)kc * (16*192*192) + e];
    float nk = sqrtf(norm2[b*1536 + 768 + h*192 + e]);
    l[u] = s * sc / fmaxf(nk, 1e-12f);
  }
  float m = fmaxf(l[0], fmaxf(l[1], l[2]));
  #pragma unroll
  for (int off = 32; off; off >>= 1) m = fmaxf(m, __shfl_xor(m, off));
  float p[3], s = 0.f;
  #pragma unroll
  for (int u = 0; u < 3; ++u){ p[u] = expf(l[u] - m); s += p[u]; }
  #pragma unroll
  for (int off = 32; off; off >>= 1) s += __shfl_xor(s, off);
  float inv = 1.f / s;
  ushort* ar = attn + ((size_t)bh * 192 + d) * 192;
  #pragma unroll
  for (int u = 0; u < 3; ++u) ar[lane + u*64] = f2bf(p[u] * inv);
}

// ---------------- out[n][h*192+d] = sum_e V[n][e] * attn[d][e] --------------
__global__ __launch_bounds__(256) void out_gemm(const ushort* __restrict__ Q,
                                                const ushort* __restrict__ attn,
                                                float* __restrict__ out){
  const int bh = blockIdx.y;
  const int b = bh >> 2, h = bh & 3;
  const int n0 = blockIdx.x * 128;
  const int t = threadIdx.x, w = t >> 6, lane = t & 63;
  const int wn = w & 1, wd = w >> 1;
  const int lr = lane & 15, lg = lane >> 4;
  f32x4 acc[4][6];
  #pragma unroll
  for (int i = 0; i < 4; ++i)
    #pragma unroll
    for (int j = 0; j < 6; ++j)
      acc[i][j] = (f32x4){0.f, 0.f, 0.f, 0.f};

  const ushort* Vbase = Q + 1536 + h * 192;
  const ushort* Abase = attn + (size_t)bh * 192 * 192;

  #pragma unroll
  for (int kk = 0; kk < 6; ++kk){
    const int e = kk * 32 + lg * 8;
    short8_t av[4], bv[6];
    #pragma unroll
    for (int f = 0; f < 4; ++f){
      int n = n0 + wn*64 + f*16 + lr;
      av[f] = *(const short8_t*)(Vbase + (size_t)(b*N_ + n) * CQ_ + e);
    }
    #pragma unroll
    for (int f = 0; f < 6; ++f){
      int d = wd*96 + f*16 + lr;
      bv[f] = *(const short8_t*)(Abase + d * 192 + e);
    }
    #pragma unroll
    for (int i = 0; i < 4; ++i)
      #pragma unroll
      for (int j = 0; j < 6; ++j)
        acc[i][j] = __builtin_amdgcn_mfma_f32_16x16x32_bf16(av[i], bv[j], acc[i][j], 0, 0, 0);
  }
  #pragma unroll
  for (int i = 0; i < 4; ++i)
    #pragma unroll
    for (int j = 0; j < 6; ++j)
      #pragma unroll
      for (int r = 0; r < 4; ++r){
        int n = n0 + wn*64 + i*16 + lg*4 + r;
        int c = h*192 + wd*96 + j*16 + lr;
        out[(size_t)(b*N_ + n) * 768 + c] = acc[i][j][r];
      }
}

// ---------------------------------------------------------------------------
extern "C" void kernel_launch(void* const* d_in, const int* in_sizes, int n_in,
                              void* d_out, int out_size, void* d_ws, size_t ws_size,
                              hipStream_t stream){
  const float* x    = (const float*)d_in[0];
  const float* Wq   = (const float*)d_in[1];
  const float* temp = (const float*)d_in[2];
  float* out = (float*)d_out;
  char* ws = (char*)d_ws;

  // workspace layout (bytes) — S_part/attn overlay xb (dead after gemm_qkvv)
  ushort* xb    = (ushort*)(ws + 0);          //  50,331,648 (dead after gemm)
  float*  S_part= (float*)(ws + 0);           //  37,748,736 (16 slices)
  ushort* attn  = (ushort*)(ws + 37748736);   //   1,179,648
  ushort* Wb    = (ushort*)(ws + 50331648);   //   3,538,944
  ushort* qkvv  = (ushort*)(ws + 53870592);   // 150,994,944
  float*  norm2 = (float*)(ws + 204865536);   //      24,576

  static_assert(sizeof(ushort) == 2, "");
  hipFuncSetAttribute((const void*)gemm_qkvv,
                      hipFuncAttributeMaxDynamicSharedMemorySize, 65536);

  cvt_all<<<26304, 256, 0, stream>>>(x, xb, Wq, Wb, norm2);

  gemm_qkvv<<<4608, 256, 65536, stream>>>(xb, Wb, qkvv, norm2);

  gram_mfma<<<dim3(16, 16), 512, 0, stream>>>(qkvv, S_part);
  softmax_k<<<768, 256, 0, stream>>>(S_part, norm2, temp, attn);
  out_gemm<<<dim3(64, 16), 256, 0, stream>>>(qkvv, attn, out);
}